// Round 18
// baseline (231.926 us; speedup 1.0000x reference)
//
#include <hip/hip_runtime.h>

#define NN 8
#define HH 512
#define WW 512
#define CC 3
#define KK 5
#define PADP 2
#define WROWF (WW * CC)          // 1536 floats per image row
#define NBLOCKS 4096             // (n, h-pair, half-row walk): 8 * 256 * 2

typedef float f4a __attribute__((ext_vector_type(4), aligned(4)));

struct Row { f4a L0, L1, L2, L3; };   // 15-float window f0..f14 (L3 overlaps at f11)

__device__ __forceinline__ void load_row(const float* rb, Row& r) {
    r.L0 = *(const f4a*)(rb);
    r.L1 = *(const f4a*)(rb + 4);
    r.L2 = *(const f4a*)(rb + 8);
    r.L3 = *(const f4a*)(rb + 11);
}

// wp is a register array (constant indices only)
__device__ __forceinline__ void fma_row(const Row& r, const float* wp,
                                        float& a0, float& a1, float& a2) {
    const float w0 = wp[0], w1 = wp[1], w2 = wp[2], w3 = wp[3], w4 = wp[4];
    a0 = fmaf(r.L0[0], w0, a0); a1 = fmaf(r.L0[1], w0, a1); a2 = fmaf(r.L0[2], w0, a2);
    a0 = fmaf(r.L0[3], w1, a0); a1 = fmaf(r.L1[0], w1, a1); a2 = fmaf(r.L1[1], w1, a2);
    a0 = fmaf(r.L1[2], w2, a0); a1 = fmaf(r.L1[3], w2, a1); a2 = fmaf(r.L2[0], w2, a2);
    a0 = fmaf(r.L2[1], w3, a0); a1 = fmaf(r.L2[2], w3, a1); a2 = fmaf(r.L2[3], w3, a2);
    a0 = fmaf(r.L3[1], w4, a0); a1 = fmaf(r.L3[2], w4, a1); a2 = fmaf(r.L3[3], w4, a2);
}

#define GLDS16(gp, lp) __builtin_amdgcn_global_load_lds( \
    (const __attribute__((address_space(1))) void*)(gp), \
    (__attribute__((address_space(3))) void*)(lp), 16, 0, 0)
#define GLDS4(gp, lp) __builtin_amdgcn_global_load_lds( \
    (const __attribute__((address_space(1))) void*)(gp), \
    (__attribute__((address_space(3))) void*)(lp), 4, 0, 0)

// stage both rows' weights for wseg index jj into the (single) LDS buffer pair
#define STAGE2(jj) do {                                                  \
    const long _p = (long)(nHH + h0) * WW + (((half << 2) | (jj)) << 6); \
    const char* _s0 = (const char*)(wt + _p * (KK * KK));                \
    const char* _s1 = (const char*)(wt + (_p + WW) * (KK * KK));         \
    _Pragma("unroll")                                                    \
    for (int _it = 0; _it < 6; ++_it)                                    \
        GLDS16(_s0 + _it * 1024 + lane * 16, wldsA + _it * 256);         \
    GLDS4(_s0 + 6144 + lane * 4, wldsA + 1536);                          \
    _Pragma("unroll")                                                    \
    for (int _it = 0; _it < 6; ++_it)                                    \
        GLDS16(_s1 + _it * 1024 + lane * 16, wldsB + _it * 256);         \
    GLDS4(_s1 + 6144 + lane * 4, wldsB + 1536);                          \
} while (0)

__global__ __launch_bounds__(64, 3) void conv_local_kernel(
    const float* __restrict__ in,   // (N,H,W,C)
    const float* __restrict__ wt,   // (N,H,W,25)
    float* __restrict__ out)        // (N,H,W,C)
{
    __shared__ float wldsA[64 * KK * KK];   // 6.4 KB: row h0 weights
    __shared__ float wldsB[64 * KK * KK];   // 6.4 KB: row h0+1 weights

    const int lane = threadIdx.x;
    // bijective XCD swizzle: 4096 = 8 x 512; XCD k streams image k only
    const int b    = ((blockIdx.x & 7) << 9) | (blockIdx.x >> 3);
    const int n    = b >> 9;
    const int rem  = b & 511;
    const int hp   = rem >> 1;         // 0..255
    const int half = rem & 1;          // walks wseg half*4 .. half*4+3
    const int h0   = hp << 1;          // 0..510 (rows h0, h0+1)
    const int nHH  = n * HH;

    const float* inb  = in + (size_t)n * (HH * WW * CC);
    const bool  rowok = (hp >= 1) && (hp <= 254);   // h0-2 >= 0 && h0+4 <= 511

    STAGE2(0);                          // prologue: step-0 weights in flight

#pragma unroll 1
    for (int j = 0; j < 4; ++j) {
        const int  w0 = (((half << 2) | j)) << 6;
        const long p0 = (long)(nHH + h0) * WW + w0;
        const long p1 = p0 + WW;
        const bool fast = rowok && (w0 != 0) && (w0 != WW - 64);

        Row R0, R1, R2, R3, R4, R5;
        if (fast) {
            // inputs issued before the drain: latency overlaps the weight wait
            const float* rb = inb + ((long)(h0 - PADP) * WW + (w0 + lane - PADP)) * CC;
            load_row(rb + 0 * WROWF, R0);
            load_row(rb + 1 * WROWF, R1);
            load_row(rb + 2 * WROWF, R2);
            load_row(rb + 3 * WROWF, R3);
            load_row(rb + 4 * WROWF, R4);
            load_row(rb + 5 * WROWF, R5);
        }
        asm volatile("s_waitcnt vmcnt(0)" ::: "memory");   // weights j + inputs done
        __builtin_amdgcn_sched_barrier(0);

        // ---- hoist this step's weights LDS -> registers (constant indices) ----
        float wA[KK * KK], wB[KK * KK];
        {
            const float* wp0 = &wldsA[lane * (KK * KK)];
            const float* wp1 = &wldsB[lane * (KK * KK)];
#pragma unroll
            for (int k = 0; k < KK * KK; ++k) wA[k] = wp0[k];
#pragma unroll
            for (int k = 0; k < KK * KK; ++k) wB[k] = wp1[k];
        }
        // all ds_reads of the buffers complete -> safe to overwrite with next stage
        asm volatile("s_waitcnt lgkmcnt(0)" ::: "memory");
        __builtin_amdgcn_sched_barrier(0);

        if (j < 3) STAGE2(j + 1);       // next step's weights stream DURING compute

        if (fast) {
            float a0 = 0.f, a1 = 0.f, a2 = 0.f;   // px (h0,   w)
            float c0 = 0.f, c1 = 0.f, c2 = 0.f;   // px (h0+1, w)
            fma_row(R0, wA + 0,  a0, a1, a2);
            fma_row(R1, wA + 5,  a0, a1, a2);
            fma_row(R1, wB + 0,  c0, c1, c2);
            fma_row(R2, wA + 10, a0, a1, a2);
            fma_row(R2, wB + 5,  c0, c1, c2);
            fma_row(R3, wA + 15, a0, a1, a2);
            fma_row(R3, wB + 10, c0, c1, c2);
            fma_row(R4, wA + 20, a0, a1, a2);
            fma_row(R4, wB + 15, c0, c1, c2);
            fma_row(R5, wB + 20, c0, c1, c2);

            float* o0 = out + (p0 + lane) * CC;
            o0[0] = a0; o0[1] = a1; o0[2] = a2;
            float* o1 = out + (p1 + lane) * CC;
            o1[0] = c0; o1[1] = c1; o1[2] = c2;
        } else {
            // border step: predicated scalar path, weights from registers
#pragma unroll
            for (int px = 0; px < 2; ++px) {
                const int hh = h0 + px;
                const int w  = w0 + lane;
                const float* wp = px ? wB : wA;
                float a0 = 0.f, a1 = 0.f, a2 = 0.f;
#pragma unroll
                for (int dh = 0; dh < KK; ++dh) {
                    const int ih = hh + dh - PADP;
                    const bool rok = ((unsigned)ih < (unsigned)HH);
#pragma unroll
                    for (int dw = 0; dw < KK; ++dw) {
                        const int iw = w + dw - PADP;
                        const bool ok = rok && ((unsigned)iw < (unsigned)WW);
                        const float* p = inb + ((long)(ih * WW + iw)) * CC;
                        float v0 = ok ? p[0] : 0.f;
                        float v1 = ok ? p[1] : 0.f;
                        float v2 = ok ? p[2] : 0.f;
                        const float wv = wp[dh * KK + dw];
                        a0 = fmaf(v0, wv, a0);
                        a1 = fmaf(v1, wv, a1);
                        a2 = fmaf(v2, wv, a2);
                    }
                }
                float* o = out + ((long)(nHH + hh) * WW + w) * CC;
                o[0] = a0; o[1] = a1; o[2] = a2;
            }
        }
    }
}

extern "C" void kernel_launch(void* const* d_in, const int* in_sizes, int n_in,
                              void* d_out, int out_size, void* d_ws, size_t ws_size,
                              hipStream_t stream) {
    const float* in = (const float*)d_in[0];   // (8,512,512,3) f32
    const float* wt = (const float*)d_in[1];   // (8,512,512,25) f32
    float* out = (float*)d_out;                // (8,512,512,3) f32

    conv_local_kernel<<<NBLOCKS, 64, 0, stream>>>(in, wt, out);
}